// Round 17
// baseline (667.954 us; speedup 1.0000x reference)
//
#include <hip/hip_runtime.h>

typedef _Float16 f16;
typedef f16 f16x2 __attribute__((ext_vector_type(2)));
typedef f16 f16x4 __attribute__((ext_vector_type(4)));
typedef f16 f16x8 __attribute__((ext_vector_type(8)));
typedef float f32x4 __attribute__((ext_vector_type(4)));

union v8split { f16x8 v8; f16x2 v2[4]; };

// ---------------- d_ws layout: fragment-ordered weights only ----------------
#define WQF_OFF 0
#define WPF_OFF (768 * 256 * 2)              // 393216
#define WS_NEED (WPF_OFF + 256 * 256 * 2)    // 524288

// LDS: bufX0 32KB | bufX1 32KB | qkv [64t][1536B] 96KB = 160KB exactly.
// Block = one (slab, kw-QUAD): owns FULL 64B lines of x (k 0..15) and out
// -> no cross-block line sharing at all. r16's pair blocks owned half-lines
// and paid RMW on writes (WRITE 398MB, FETCH +134MB) — quads fix that.
#define QKV_LDS_OFF 65536
#define SMEM_TOTAL 163840

// fp32 -> fp16 weight conversion into FRAGMENT ORDER (r14-validated).
__global__ __launch_bounds__(256) void cvt_weights_frag_k(
    const float* __restrict__ wq, const float* __restrict__ wp,
    f16* __restrict__ wq_f, f16* __restrict__ wp_f) {
  int tid2 = blockIdx.x * 256 + threadIdx.x;  // 24576 (wq) + 8192 (wp)
  if (tid2 < 24576) {
    const int lane = tid2 & 63, kt = (tid2 >> 6) & 7, f0 = tid2 >> 9;
    const float* s = wq + (size_t)(f0 * 16 + (lane & 15)) * 256 + kt * 32 + (lane >> 4) * 8;
    f16* d = wq_f + (size_t)tid2 * 8;
#pragma unroll
    for (int e = 0; e < 8; ++e) d[e] = (f16)s[e];
  } else if (tid2 < 32768) {
    const int t2 = tid2 - 24576;
    const int lane = t2 & 63, kt = (t2 >> 6) & 7, f0 = t2 >> 9;
    const float* s = wp + (size_t)(f0 * 16 + (lane & 15)) * 256 + kt * 32 + (lane >> 4) * 8;
    f16* d = wp_f + (size_t)t2 * 8;
#pragma unroll
    for (int e = 0; e < 8; ++e) d[e] = (f16)s[e];
  }
}

// XOR-swizzled addr into a 64-row x 512B tile (xw / out2) — r10/r16-validated.
__device__ __forceinline__ char* xwp(char* s, int row, int colbyte) {
  return s + row * 512 + (colbyte ^ (((row ^ (row >> 3)) & 7) << 4));
}
// qkv tile [64 t][768 f], row stride 1536B — r10/r16-validated.
__device__ __forceinline__ char* qvp(char* s, int t, int fbyte) {
  return s + QKV_LDS_OFF + t * 1536 + (fbyte ^ ((t & 7) << 4));
}

// DPP quad_perm swaps: lane^1 and lane^2 (r11/r16-validated attention merge)
__device__ __forceinline__ float qswap1f(float v) {
  int x = __builtin_bit_cast(int, v);
  x = __builtin_amdgcn_update_dpp(0, x, 0xB1, 0xf, 0xf, true);  // [1,0,3,2]
  return __builtin_bit_cast(float, x);
}
__device__ __forceinline__ float qswap2f(float v) {
  int x = __builtin_bit_cast(int, v);
  x = __builtin_amdgcn_update_dpp(0, x, 0x4E, 0xf, 0xf, true);  // [2,3,0,1]
  return __builtin_bit_cast(float, x);
}

#if __has_builtin(__builtin_amdgcn_fdot2)
__device__ __forceinline__ float fdot2f(f16x2 a, f16x2 b, float c) {
  return __builtin_amdgcn_fdot2(a, b, c, false);
}
#else
__device__ __forceinline__ float fdot2f(f16x2 a, f16x2 b, float c) {
  return c + (float)a[0] * (float)b[0] + (float)a[1] * (float)b[1];
}
#endif

// ---- Fully fused kw-QUAD kernel. Grid 512 = qd(1 hi bit) x slab(256 lo).
// Block owns kw = 4qd..4qd+3 of one slab, processed as two pairs.
// Pair pA stages k = qd*16 + pA*8 .. +8 (32B) of each x row; the two pairs
// of one block consume the SAME 64B lines ~10us apart -> L2-hit (per-XCD
// inter-pass footprint ~4MB). Writes likewise merge to full lines in L2.
__global__ __launch_bounds__(1024) void win_k(
    const float* __restrict__ x, const f16* __restrict__ wq_f,
    const f16* __restrict__ wp_f, float* __restrict__ out) {
  extern __shared__ char smem[];
  const int blk = blockIdx.x;
  const int slab = blk & 255, qd = blk >> 8;
  const int b = slab >> 6, zi = (slab >> 3) & 7, yj = slab & 7;
  const int tid = threadIdx.x, wv = tid >> 6, lane = tid & 63;
  const int lcol = lane & 15, lq = lane >> 4;
  char* bufX0 = smem;
  char* bufX1 = smem + 32768;

  // GEMM1 (r14/r16-validated): wave = 48 f-cols, acc[3][4], fragment weights.
  auto G1 = [&](char* buf) {
    f32x4 acc[3][4] = {};
    const f16* wbase = wq_f + ((size_t)wv * 3 * 8) * 64 * 8 + lane * 8;
#pragma unroll
    for (int kt = 0; kt < 8; ++kt) {
      f16x8 bf[4];
#pragma unroll
      for (int nt = 0; nt < 4; ++nt)
        bf[nt] = *(const f16x8*)xwp(buf, nt * 16 + lcol, kt * 64 + lq * 16);
#pragma unroll
      for (int ms = 0; ms < 3; ++ms) {
        f16x8 af = *(const f16x8*)(wbase + (size_t)(ms * 8 + kt) * 512);
#pragma unroll
        for (int nt = 0; nt < 4; ++nt)
          acc[ms][nt] = __builtin_amdgcn_mfma_f32_16x16x32_f16(af, bf[nt], acc[ms][nt], 0, 0, 0);
      }
    }
    const int fs = wv * 48;
#pragma unroll
    for (int ms = 0; ms < 3; ++ms)
#pragma unroll
      for (int nt = 0; nt < 4; ++nt) {
        f16x4 hv;
        hv[0] = (f16)acc[ms][nt][0]; hv[1] = (f16)acc[ms][nt][1];
        hv[2] = (f16)acc[ms][nt][2]; hv[3] = (f16)acc[ms][nt][3];
        *(f16x4*)qvp(smem, nt * 16 + lcol, (fs + ms * 16 + lq * 4) * 2) = hv;
      }
  };

  // Attention (r12/r16-validated): wave owns 4 tokens, lane=(tt<<4|h<<2|dq),
  // d-quarter per lane, DPP merges lane^1 then lane^2. out2 -> buf.
  auto ATTN = [&](char* buf) {
    const int tt = lane >> 4, h = (lane >> 2) & 3, dq = lane & 3;
    const int t = wv * 4 + tt;
    const int db = dq * 32;

    f16x2 q2[8];
#pragma unroll
    for (int j = 0; j < 2; ++j) {
      v8split u;
      u.v8 = *(const f16x8*)qvp(smem, t, h * 128 + db + j * 16);
      q2[j * 4 + 0] = u.v2[0]; q2[j * 4 + 1] = u.v2[1];
      q2[j * 4 + 2] = u.v2[2]; q2[j * 4 + 3] = u.v2[3];
    }
    float s[4];
#pragma unroll
    for (int g = 0; g < 4; ++g) {
      float a = 0.f;
#pragma unroll
      for (int j = 0; j < 2; ++j) {
        v8split u;
        u.v8 = *(const f16x8*)qvp(smem, t, 512 + g * 128 + db + j * 16);
        a = fdot2f(q2[j * 4 + 0], u.v2[0], a);
        a = fdot2f(q2[j * 4 + 1], u.v2[1], a);
        a = fdot2f(q2[j * 4 + 2], u.v2[2], a);
        a = fdot2f(q2[j * 4 + 3], u.v2[3], a);
      }
      s[g] = a;
    }
#pragma unroll
    for (int g = 0; g < 4; ++g) {
      s[g] += qswap1f(s[g]);
      s[g] += qswap2f(s[g]);
    }
    float mx = -1e30f;
#pragma unroll
    for (int g = 0; g < 4; ++g) {
      float v = fminf(fmaxf(s[g] * 0.125f, -10.f), 10.f);  // clip BEFORE softmax
      s[g] = v; mx = fmaxf(mx, v);
    }
    float sum = 0.f;
#pragma unroll
    for (int g = 0; g < 4; ++g) { s[g] = __expf(s[g] - mx); sum += s[g]; }
    float inv = 1.f / sum;
#pragma unroll
    for (int g = 0; g < 4; ++g) s[g] *= inv;

    float o[16] = {};
#pragma unroll
    for (int g = 0; g < 4; ++g) {
      float p = s[g];
#pragma unroll
      for (int j = 0; j < 2; ++j) {
        v8split u;
        u.v8 = *(const f16x8*)qvp(smem, t, 1024 + g * 128 + db + j * 16);
#pragma unroll
        for (int i = 0; i < 4; ++i) {
          o[j * 8 + 2 * i]     += p * (float)u.v2[i][0];
          o[j * 8 + 2 * i + 1] += p * (float)u.v2[i][1];
        }
      }
    }
    const int row = h * 16 + (t >> 2);
    const int cb0 = (t & 3) * 128 + db;
#pragma unroll
    for (int j = 0; j < 2; ++j) {
      f16x8 ov;
      ov[0] = (f16)o[j * 8 + 0]; ov[1] = (f16)o[j * 8 + 1];
      ov[2] = (f16)o[j * 8 + 2]; ov[3] = (f16)o[j * 8 + 3];
      ov[4] = (f16)o[j * 8 + 4]; ov[5] = (f16)o[j * 8 + 5];
      ov[6] = (f16)o[j * 8 + 6]; ov[7] = (f16)o[j * 8 + 7];
      *(f16x8*)xwp(buf, row, cb0 + j * 16) = ov;
    }
  };

  // GEMM2 compute only (store deferred): wave = 16 c3-cols, fblock = wv.
  auto G2C = [&](char* buf, f32x4* acc2) {
    const f16* bp = wp_f + ((size_t)wv * 8) * 64 * 8 + lane * 8;
#pragma unroll
    for (int kt = 0; kt < 8; ++kt) {
      f16x8 bfr = *(const f16x8*)(bp + (size_t)kt * 512);
#pragma unroll
      for (int mt = 0; mt < 4; ++mt) {
        f16x8 afr = *(const f16x8*)xwp(buf, mt * 16 + lcol, kt * 64 + lq * 16);
        acc2[mt] = __builtin_amdgcn_mfma_f32_16x16x32_f16(afr, bfr, acc2[mt], 0, 0, 0);
      }
    }
  };

  const int c3 = wv * 16 + lcol;

#pragma unroll 1
  for (int pA = 0; pA < 2; ++pA) {
    // stage pair: 32B per thread-row (k = qd*16 + pA*8 .. +8), windows
    // kw = qd*4 + pA*2 (+0 -> bufX0, +1 -> bufX1). r16-validated mapping.
    {
      const float* xb = x + (size_t)b * 8388608 + zi * 4096 + yj * 128 + qd * 16 + pA * 8;
#pragma unroll
      for (int it = 0; it < 4; ++it) {
        int idx = it * 1024 + tid;  // (c, a, bb)
        int c = idx >> 4, a = (idx >> 2) & 3, bb = idx & 3;
        const float* p = xb + (size_t)c * 32768 + a * 1024 + bb * 32;
        float4 v0 = *(const float4*)(p);
        float4 v1 = *(const float4*)(p + 4);
        const int row = c >> 2, cb = (c & 3) * 128 + a * 32 + bb * 8;
        f16x4 h0, h1;
        h0[0] = (f16)v0.x; h0[1] = (f16)v0.y; h0[2] = (f16)v0.z; h0[3] = (f16)v0.w;
        h1[0] = (f16)v1.x; h1[1] = (f16)v1.y; h1[2] = (f16)v1.z; h1[3] = (f16)v1.w;
        *(f16x4*)xwp(bufX0, row, cb) = h0;
        *(f16x4*)xwp(bufX1, row, cb) = h1;
      }
    }
    __syncthreads();

    G1(bufX0);
    __syncthreads();            // qkv(w0) ready
    ATTN(bufX0);                // out2(w0) -> bufX0
    __syncthreads();            // out2(w0) ready; qkv free
    f32x4 a0[4] = {};
    G2C(bufX0, a0);             // reads bufX0 out2
    G1(bufX1);                  // writes qkv(w1), reads bufX1 xw
    __syncthreads();            // qkv(w1) ready
    ATTN(bufX1);                // out2(w1) -> bufX1
    __syncthreads();            // out2(w1) ready
    f32x4 a1[4] = {};
    G2C(bufX1, a1);

    // store pair: 32B contiguous per thread-row; sibling pair (same block)
    // writes the adjacent 32B -> full 64B line merges in L2.
    // out[b][c3][zi*4+mt][yj*4+lq][qd*16 + pA*8 + w*4 + r] (r16-validated).
    {
      float* ob = out + (size_t)b * 8388608 + zi * 4096 + yj * 128 + qd * 16 + pA * 8;
#pragma unroll
      for (int mt = 0; mt < 4; ++mt) {
        float* d = ob + (size_t)c3 * 32768 + mt * 1024 + lq * 32;
        float4 v0, v1;
        v0.x = a0[mt][0]; v0.y = a0[mt][1]; v0.z = a0[mt][2]; v0.w = a0[mt][3];
        v1.x = a1[mt][0]; v1.y = a1[mt][1]; v1.z = a1[mt][2]; v1.w = a1[mt][3];
        *(float4*)(d) = v0;
        *(float4*)(d + 4) = v1;
      }
    }
    __syncthreads();            // all reads of bufX0/X1 done before restage
  }
}

extern "C" void kernel_launch(void* const* d_in, const int* in_sizes, int n_in,
                              void* d_out, int out_size, void* d_ws, size_t ws_size,
                              hipStream_t stream) {
  const float* x = (const float*)d_in[0];
  const float* wq = (const float*)d_in[1];
  const float* wp = (const float*)d_in[2];
  float* out = (float*)d_out;
  char* ws = (char*)d_ws;
  f16* wq_f = (f16*)(ws + WQF_OFF);
  f16* wp_f = (f16*)(ws + WPF_OFF);

  (void)hipFuncSetAttribute((const void*)win_k,
                            hipFuncAttributeMaxDynamicSharedMemorySize, SMEM_TOTAL);

  cvt_weights_frag_k<<<128, 256, 0, stream>>>(wq, wp, wq_f, wp_f);
  win_k<<<512, 1024, SMEM_TOTAL, stream>>>(x, wq_f, wp_f, out);
}

// Round 18
// 233.053 us; speedup vs baseline: 2.8661x; 2.8661x over previous
//
#include <hip/hip_runtime.h>

typedef _Float16 f16;
typedef f16 f16x2 __attribute__((ext_vector_type(2)));
typedef f16 f16x4 __attribute__((ext_vector_type(4)));
typedef f16 f16x8 __attribute__((ext_vector_type(8)));
typedef float f32x4 __attribute__((ext_vector_type(4)));

union v8split { f16x8 v8; f16x2 v2[4]; };

// ---------------- d_ws layout ----------------
#define WQF_OFF 0
#define WPF_OFF (768 * 256 * 2)                         // 393216
#define XW_OFF  (WPF_OFF + 256 * 256 * 2)               // 524288
#define O2_OFF  (XW_OFF + (size_t)2048 * 16384 * 2)     // +67108864
#define WS_NEED (O2_OFF + (size_t)2048 * 16384 * 2)     // 134742016

// LDS (half-window block): xw/out2 tile [32][512B] = 16KB | qkv [32t][1536B]
// = 48KB -> 64KB total -> 2 independent blocks/CU (r11 shape, r14 weights).
#define QKV_LDS_OFF 16384
#define SMEM_TOTAL 65536

// fp32 -> fp16 weight conversion into FRAGMENT ORDER (r14-validated):
// fragment (f0, kt) at lane l = contiguous 16B at frag[((f0*8+kt)*64+l)*8].
__global__ __launch_bounds__(256) void cvt_weights_frag_k(
    const float* __restrict__ wq, const float* __restrict__ wp,
    f16* __restrict__ wq_f, f16* __restrict__ wp_f) {
  int tid2 = blockIdx.x * 256 + threadIdx.x;  // 24576 (wq) + 8192 (wp)
  if (tid2 < 24576) {
    const int lane = tid2 & 63, kt = (tid2 >> 6) & 7, f0 = tid2 >> 9;
    const float* s = wq + (size_t)(f0 * 16 + (lane & 15)) * 256 + kt * 32 + (lane >> 4) * 8;
    f16* d = wq_f + (size_t)tid2 * 8;
#pragma unroll
    for (int e = 0; e < 8; ++e) d[e] = (f16)s[e];
  } else if (tid2 < 32768) {
    const int t2 = tid2 - 24576;
    const int lane = t2 & 63, kt = (t2 >> 6) & 7, f0 = t2 >> 9;
    const float* s = wp + (size_t)(f0 * 16 + (lane & 15)) * 256 + kt * 32 + (lane >> 4) * 8;
    f16* d = wp_f + (size_t)t2 * 8;
#pragma unroll
    for (int e = 0; e < 8; ++e) d[e] = (f16)s[e];
  }
}

// XOR-swizzled addr into a 32-row x 512B tile (xw / out2) — r11-validated.
__device__ __forceinline__ char* xwp(char* s, int row, int colbyte) {
  return s + row * 512 + (colbyte ^ (((row ^ (row >> 3)) & 7) << 4));
}
// qkv tile [32 t][768 f], row stride 1536B — r11-validated.
__device__ __forceinline__ char* qvp(char* s, int t, int fbyte) {
  return s + QKV_LDS_OFF + t * 1536 + (fbyte ^ ((t & 7) << 4));
}

// DPP quad_perm swaps: lane^1 and lane^2 (r11-validated attention merge)
__device__ __forceinline__ float qswap1f(float v) {
  int x = __builtin_bit_cast(int, v);
  x = __builtin_amdgcn_update_dpp(0, x, 0xB1, 0xf, 0xf, true);  // [1,0,3,2]
  return __builtin_bit_cast(float, x);
}
__device__ __forceinline__ float qswap2f(float v) {
  int x = __builtin_bit_cast(int, v);
  x = __builtin_amdgcn_update_dpp(0, x, 0x4E, 0xf, 0xf, true);  // [2,3,0,1]
  return __builtin_bit_cast(float, x);
}

#if __has_builtin(__builtin_amdgcn_fdot2)
__device__ __forceinline__ float fdot2f(f16x2 a, f16x2 b, float c) {
  return __builtin_amdgcn_fdot2(a, b, c, false);
}
#else
__device__ __forceinline__ float fdot2f(f16x2 a, f16x2 b, float c) {
  return c + (float)a[0] * (float)b[0] + (float)a[1] * (float)b[1];
}
#endif

// ---- K1: gather/transpose x -> xw_all, per-HALF-WINDOW contiguous 16KB
// pre-swizzled tiles (r11-validated mapping; full 128B-line x reads).
__global__ __launch_bounds__(256) void gather_k(const float* __restrict__ x,
                                                f16* __restrict__ xw_all) {
  const int g = blockIdx.x >> 4, cb = blockIdx.x & 15;
  const int b = g >> 6, iw = (g >> 3) & 7, jw = g & 7;
  const int tid = threadIdx.x;
  const int c = cb * 16 + (tid >> 4), a = (tid >> 2) & 3, bb = tid & 3;
  const float* src = x + (size_t)b * 8388608 + (size_t)c * 32768 +
                     (iw * 4 + a) * 1024 + (jw * 4 + bb) * 32;
  const int t = c >> 2, hb = t >> 5, tl = t & 31;
  const int c2b = (c & 3) * 128 + a * 32 + bb * 8;
  const int byt = tl * 512 + (c2b ^ (((tl ^ (tl >> 3)) & 7) << 4));
  char* wbase = (char*)(xw_all + (size_t)(g * 16 + hb) * 8192) + byt;
#pragma unroll
  for (int kw = 0; kw < 8; ++kw) {
    float4 v = *(const float4*)(src + kw * 4);
    f16x4 h;
    h[0] = (f16)v.x; h[1] = (f16)v.y; h[2] = (f16)v.z; h[3] = (f16)v.w;
    *(f16x4*)(wbase + (size_t)kw * 32768) = h;
  }
}

// ---- K2: fused half-window kernel (32 tokens, r11-validated mappings) with
// FRAGMENT-ORDER weights (r14's +52% lever). 4096 blocks x 512 thr, 64KB LDS
// -> 2 independent blocks/CU whose barrier drains overlap each other.
__global__ __launch_bounds__(512) void win_attn_k(
    const f16* __restrict__ xw_all, const f16* __restrict__ wq_f,
    const f16* __restrict__ wp_f, f16* __restrict__ o2T) {
  extern __shared__ char smem[];
  const int hw = blockIdx.x;              // half-window id
  const int wi = hw >> 1, hb = hw & 1;    // window, half (tokens hb*32..+32)
  const int tid = threadIdx.x, wv = tid >> 6, lane = tid & 63;
  const int lcol = lane & 15, lq = lane >> 4;

  // Phase 1: 16KB pre-swizzled xw tile -> LDS (linear dest, 2x16B/thread).
  {
    const char* g = (const char*)(xw_all + (size_t)hw * 8192) + tid * 16;
#pragma unroll
    for (int i = 0; i < 2; ++i)
      __builtin_amdgcn_global_load_lds(
          (const __attribute__((address_space(1))) void*)(g + i * 8192),
          (__attribute__((address_space(3))) void*)(smem + tid * 16 + i * 8192),
          16, 0, 0);
  }
  __syncthreads();

  // Phase 2: GEMM1 qkv[32t x 768f]. Wave = 96 f-cols (2 halves of 48);
  // af loads per-wave contiguous 1KB fragments from wq_f.
#pragma unroll 1
  for (int half = 0; half < 2; ++half) {
    f32x4 acc[3][2] = {};
    const f16* wbase = wq_f + (size_t)(wv * 6 + half * 3) * 8 * 512 + lane * 8;
#pragma unroll
    for (int kt = 0; kt < 8; ++kt) {
      f16x8 bf[2];
#pragma unroll
      for (int nt = 0; nt < 2; ++nt)
        bf[nt] = *(const f16x8*)xwp(smem, nt * 16 + lcol, kt * 64 + lq * 16);
#pragma unroll
      for (int ms = 0; ms < 3; ++ms) {
        f16x8 af = *(const f16x8*)(wbase + (size_t)(ms * 8 + kt) * 512);
#pragma unroll
        for (int nt = 0; nt < 2; ++nt)
          acc[ms][nt] = __builtin_amdgcn_mfma_f32_16x16x32_f16(af, bf[nt], acc[ms][nt], 0, 0, 0);
      }
    }
    // D: col(lane&15)=local token, row(lq*4+r)=feature -> f16x4 qkv[t][f].
    const int fs = wv * 96 + half * 48;
#pragma unroll
    for (int ms = 0; ms < 3; ++ms)
#pragma unroll
      for (int nt = 0; nt < 2; ++nt) {
        f16x4 hv;
        hv[0] = (f16)acc[ms][nt][0]; hv[1] = (f16)acc[ms][nt][1];
        hv[2] = (f16)acc[ms][nt][2]; hv[3] = (f16)acc[ms][nt][3];
        *(f16x4*)qvp(smem, nt * 16 + lcol, (fs + ms * 16 + lq * 4) * 2) = hv;
      }
  }
  __syncthreads();

  // Phase 3: per-token attention (r11-validated). Wave owns 4 tokens;
  // lane = (tt<<4|h<<2|dq); d-quarter per lane; DPP merges lane^1, lane^2.
  {
    const int tt = lane >> 4, h = (lane >> 2) & 3, dq = lane & 3;
    const int tl = wv * 4 + tt;
    const int db = dq * 32;

    f16x2 q2[8];
#pragma unroll
    for (int j = 0; j < 2; ++j) {
      v8split u;
      u.v8 = *(const f16x8*)qvp(smem, tl, h * 128 + db + j * 16);
      q2[j * 4 + 0] = u.v2[0]; q2[j * 4 + 1] = u.v2[1];
      q2[j * 4 + 2] = u.v2[2]; q2[j * 4 + 3] = u.v2[3];
    }
    float s[4];
#pragma unroll
    for (int g = 0; g < 4; ++g) {
      float a = 0.f;
#pragma unroll
      for (int j = 0; j < 2; ++j) {
        v8split u;
        u.v8 = *(const f16x8*)qvp(smem, tl, 512 + g * 128 + db + j * 16);
        a = fdot2f(q2[j * 4 + 0], u.v2[0], a);
        a = fdot2f(q2[j * 4 + 1], u.v2[1], a);
        a = fdot2f(q2[j * 4 + 2], u.v2[2], a);
        a = fdot2f(q2[j * 4 + 3], u.v2[3], a);
      }
      s[g] = a;
    }
#pragma unroll
    for (int g = 0; g < 4; ++g) {
      s[g] += qswap1f(s[g]);   // merge dq^1
      s[g] += qswap2f(s[g]);   // merge dq^2 -> full 64-d dot on all 4 lanes
    }

    float mx = -1e30f;
#pragma unroll
    for (int g = 0; g < 4; ++g) {
      float v = fminf(fmaxf(s[g] * 0.125f, -10.f), 10.f);  // clip BEFORE softmax
      s[g] = v; mx = fmaxf(mx, v);
    }
    float sum = 0.f;
#pragma unroll
    for (int g = 0; g < 4; ++g) { s[g] = __expf(s[g] - mx); sum += s[g]; }
    float inv = 1.f / sum;
#pragma unroll
    for (int g = 0; g < 4; ++g) s[g] *= inv;

    float o[16] = {};
#pragma unroll
    for (int g = 0; g < 4; ++g) {
      float p = s[g];
#pragma unroll
      for (int j = 0; j < 2; ++j) {
        v8split u;
        u.v8 = *(const f16x8*)qvp(smem, tl, 1024 + g * 128 + db + j * 16);
#pragma unroll
        for (int i = 0; i < 4; ++i) {
          o[j * 8 + 2 * i]     += p * (float)u.v2[i][0];
          o[j * 8 + 2 * i + 1] += p * (float)u.v2[i][1];
        }
      }
    }
    // out2 tile row = h*8 + tl/4, colbyte = (tl&3)*128 + dq*32 + j*16.
    const int row = h * 8 + (tl >> 2);
    const int cb0 = (tl & 3) * 128 + db;
#pragma unroll
    for (int j = 0; j < 2; ++j) {
      f16x8 ov;
      ov[0] = (f16)o[j * 8 + 0]; ov[1] = (f16)o[j * 8 + 1];
      ov[2] = (f16)o[j * 8 + 2]; ov[3] = (f16)o[j * 8 + 3];
      ov[4] = (f16)o[j * 8 + 4]; ov[5] = (f16)o[j * 8 + 5];
      ov[6] = (f16)o[j * 8 + 6]; ov[7] = (f16)o[j * 8 + 7];
      *(f16x8*)xwp(smem, row, cb0 + j * 16) = ov;
    }
  }
  __syncthreads();

  // Phase 4: GEMM2 on the 32-row out2 tile. Wave = 32 c3-cols; bfr from
  // wp_f fragments (fblock = wv*2+nt). r11-validated t2 mapping.
  {
    f32x4 acc2[2][2] = {};
#pragma unroll
    for (int kt = 0; kt < 8; ++kt) {
      f16x8 afr[2];
#pragma unroll
      for (int mt = 0; mt < 2; ++mt)
        afr[mt] = *(const f16x8*)xwp(smem, mt * 16 + lcol, kt * 64 + lq * 16);
#pragma unroll
      for (int nt = 0; nt < 2; ++nt) {
        f16x8 bfr = *(const f16x8*)(wp_f + (size_t)(wv * 2 + nt) * 8 * 512 +
                                    (size_t)kt * 512 + lane * 8);
#pragma unroll
        for (int mt = 0; mt < 2; ++mt)
          acc2[mt][nt] = __builtin_amdgcn_mfma_f32_16x16x32_f16(afr[mt], bfr, acc2[mt][nt], 0, 0, 0);
      }
    }
    // D row i = mt*16 + lq*4 + r -> t2 = (mt*2+(lq>>1))*16 + hb*8 + (lq&1)*4 + r
    f16* ob = o2T + (size_t)wi * 16384;
    const int t2b = hb * 8 + ((lq & 1) * 4);
#pragma unroll
    for (int mt = 0; mt < 2; ++mt)
#pragma unroll
      for (int nt = 0; nt < 2; ++nt) {
        int c3 = wv * 32 + nt * 16 + lcol;
        int t2 = (mt * 2 + (lq >> 1)) * 16 + t2b;
        f16x4 hv;
        hv[0] = (f16)acc2[mt][nt][0]; hv[1] = (f16)acc2[mt][nt][1];
        hv[2] = (f16)acc2[mt][nt][2]; hv[3] = (f16)acc2[mt][nt][3];
        *(f16x4*)(ob + c3 * 64 + t2) = hv;
      }
  }
}

// ---- K3: scatter o2T (fp16, L3-hot) -> out (fp32, full 128B-line writes).
__global__ __launch_bounds__(256) void scatter_k(const f16* __restrict__ o2T,
                                                 float* __restrict__ out) {
  const int g = blockIdx.x >> 4, cb = blockIdx.x & 15;
  const int b = g >> 6, iw = (g >> 3) & 7, jw = g & 7;
  const int tid = threadIdx.x;
  const int c3 = cb * 16 + (tid >> 4), a = (tid >> 2) & 3, bb = tid & 3;
  const f16* rbase = o2T + (size_t)(g << 3) * 16384 + c3 * 64 + a * 16 + bb * 4;
  float* dst = out + (size_t)b * 8388608 + (size_t)c3 * 32768 +
               (iw * 4 + a) * 1024 + (jw * 4 + bb) * 32;
#pragma unroll
  for (int kw = 0; kw < 8; ++kw) {
    f16x4 h = *(const f16x4*)(rbase + kw * 16384);
    float4 v;
    v.x = (float)h[0]; v.y = (float)h[1]; v.z = (float)h[2]; v.w = (float)h[3];
    *(float4*)(dst + kw * 4) = v;
  }
}

extern "C" void kernel_launch(void* const* d_in, const int* in_sizes, int n_in,
                              void* d_out, int out_size, void* d_ws, size_t ws_size,
                              hipStream_t stream) {
  const float* x = (const float*)d_in[0];
  const float* wq = (const float*)d_in[1];
  const float* wp = (const float*)d_in[2];
  float* out = (float*)d_out;
  char* ws = (char*)d_ws;
  f16* wq_f = (f16*)(ws + WQF_OFF);
  f16* wp_f = (f16*)(ws + WPF_OFF);
  f16* xw_all = (f16*)(ws + XW_OFF);
  f16* o2T = (f16*)(ws + O2_OFF);

  (void)hipFuncSetAttribute((const void*)win_attn_k,
                            hipFuncAttributeMaxDynamicSharedMemorySize, SMEM_TOTAL);

  cvt_weights_frag_k<<<128, 256, 0, stream>>>(wq, wp, wq_f, wp_f);
  gather_k<<<4096, 256, 0, stream>>>(x, xw_all);
  win_attn_k<<<4096, 512, SMEM_TOTAL, stream>>>(xw_all, wq_f, wp_f, o2T);
  scatter_k<<<4096, 256, 0, stream>>>(o2T, out);
}